// Round 5
// baseline (1962.302 us; speedup 1.0000x reference)
//
#include <hip/hip_runtime.h>
#include <hip/hip_bf16.h>

// EntityAwareLSTMLayer: B=1024, T=365, DYN=32, STATIC=27, U=256 (3U=768)
// Round 5: FORCE W_hh-residual residency via inline-asm AGPR pinning.
//   - 48 B-frags (8 kchunks x 3 gates x 2 unit-groups) pinned into 192 AGPRs
//     with asm("" : "+a"(frag)); MFMA K-loop is inline asm with "a" B operands
//     (gfx950 unified file: A/B may come from AGPR, ISA sec.10).
//   - x-chunk MFMAs stay builtins (B from LDS) so the compiler inserts the
//     MFMA->VALU hazard waits before the shuffles/cell update.
//   - ig/bias floats pinned to AGPRs too; target <=64 arch VGPRs so
//     192A + 64V = 256 fits 2 waves/SIMD (launch_bounds(512,2)).
//   - Rest identical to round 4 (which passed): 128 WGs x 512 thr, M=8,
//     A=[h|x] bf16 double-buffered LDS, 1 barrier/step, shfl row-balancing.

typedef short short8 __attribute__((ext_vector_type(8)));
typedef float f32x4 __attribute__((ext_vector_type(4)));

#define T_STEPS 365
#define UNITS   256
#define G3      768
#define KTOT    288
#define MROWS   8
#define NWGS    128
#define AP      296   // padded A row length in shorts

__device__ __forceinline__ unsigned short f2bf(float x) {
    union { float f; unsigned u; } v; v.f = x;
    return (unsigned short)((v.u + 0x7FFFu + ((v.u >> 16) & 1u)) >> 16);
}
__device__ __forceinline__ float sigmoidf_(float x) {
    return 1.0f / (1.0f + __expf(-x));
}
__device__ __forceinline__ float tanhf_(float x) {
    return 1.0f - 2.0f / (1.0f + __expf(2.0f * x));
}

// Wpack[k=0..287][n=0..767] -> bf16 B-fragment layout:
//   element (k,n) at wp[((k>>3)*768 + n)*8 + (k&7)]
__global__ __launch_bounds__(256) void pack_weights(
    const float* __restrict__ w_ih, const float* __restrict__ w_hh,
    unsigned short* __restrict__ wp)
{
    int idx = blockIdx.x * 256 + threadIdx.x;
    if (idx >= KTOT * G3) return;
    int k = idx / G3, n = idx - k * G3;
    float v;
    if (k < UNITS) {
        v = w_hh[k * G3 + n];
        if ((n & 255) == k) v -= 1.0f;   // subtract eye3 tile
    } else {
        v = w_ih[(k - UNITS) * G3 + n];
    }
    wp[(((k >> 3) * G3) + n) * 8 + (k & 7)] = f2bf(v);
}

// 3 MFMAs (one per gate) for one K-chunk; B operands forced from AGPRs.
// s_nop 1 covers VALU(acc zero-init)->MFMA C-read hazard; MFMA->MFMA
// dependent chains need no wait states.
#define MFMA3A(A_, B0_, B1_, B2_)                                   \
    asm("s_nop 1\n\t"                                               \
        "v_mfma_f32_16x16x32_bf16 %0, %3, %4, %0\n\t"               \
        "v_mfma_f32_16x16x32_bf16 %1, %3, %5, %1\n\t"               \
        "v_mfma_f32_16x16x32_bf16 %2, %3, %6, %2"                   \
        : "+v"(ac0), "+v"(ac1), "+v"(ac2)                           \
        : "v"(A_), "a"(B0_), "a"(B1_), "a"(B2_))

__global__ __launch_bounds__(512, 2) void lstm_mfma(
    const float* __restrict__ x_dyn,   // [1024][365][32]
    const float* __restrict__ x_sta,   // [1024][27]
    const unsigned short* __restrict__ wp,  // packed bf16 [36][768][8]
    const float* __restrict__ w_sh,    // [27][256]
    const float* __restrict__ bias,    // [768]
    const float* __restrict__ bias_s,  // [256]
    float* __restrict__ out)           // [1024][256]
{
    __shared__ unsigned short A_s[2][16][AP];       // ~18.9 KB
    __shared__ unsigned short wih_s[4 * G3 * 8];    // 48 KB: W_ih chunks 32..35

    const int tid  = threadIdx.x;
    const int b0   = blockIdx.x * MROWS;
    const int lane = tid & 63;
    const int wv   = tid >> 6;          // wave 0..7, owns units wv*32..+31
    const int mm   = lane & 15;
    const int qq   = lane >> 4;

    // ---- load 48 B-fragments and PIN them into AGPRs (192 regs) ----
    short8 bw[8][3][2];
    #pragma unroll
    for (int ks = 0; ks < 8; ++ks)
        #pragma unroll
        for (int g = 0; g < 3; ++g)
            #pragma unroll
            for (int h = 0; h < 2; ++h) {
                bw[ks][g][h] = *(const short8*)(wp +
                    ((size_t)(ks * 4 + qq) * G3 + g * UNITS + wv * 32 + h * 16 + mm) * 8);
                asm("" : "+a"(bw[ks][g][h]));   // opaque AGPR pin, no remat
            }

    // W_ih fragment region (chunks 32..35) -> LDS
    {
        const short8* src = (const short8*)(wp + (size_t)32 * G3 * 8);
        short8* dst = (short8*)wih_s;
        for (int i = tid; i < 4 * G3; i += 512) dst[i] = src[i];
    }

    // zero both A buffers (rows 8..15 stay zero forever)
    for (int i = tid; i < 2 * 16 * AP; i += 512)
        ((unsigned short*)A_s)[i] = 0;
    __syncthreads();

    // stage x_0, prefetch x_1 (threads 0..255: one (row, feature) each)
    float xr = 0.0f;
    if (tid < MROWS * 32) {
        const int row = tid >> 5, j = tid & 31;
        A_s[0][row][UNITS + j] =
            f2bf(x_dyn[((size_t)(b0 + row) * T_STEPS + 0) * 32 + j]);
        xr = x_dyn[((size_t)(b0 + row) * T_STEPS + 1) * 32 + j];
    }

    // ---- cell mapping: lane handles units {u0,u1}, rows {row0,row0+1} ----
    const int u0   = wv * 32 + mm;
    const int u1   = u0 + 16;
    const int row0 = (qq & 1) * 4 + ((qq & 2) ? 2 : 0);

    // biases + static input gate: pinned to AGPRs to keep arch-VGPR count low
    float bA[3][2], igA[2][2];
    #pragma unroll
    for (int g = 0; g < 3; ++g) {
        bA[g][0] = bias[g * UNITS + u0];
        bA[g][1] = bias[g * UNITS + u1];
        asm("" : "+a"(bA[g][0]));
        asm("" : "+a"(bA[g][1]));
    }
    float cc[4], hp[4];
    #pragma unroll
    for (int h = 0; h < 2; ++h)
        #pragma unroll
        for (int r = 0; r < 2; ++r) {
            const int u = h ? u1 : u0;
            float s = bias_s[u];
            #pragma unroll
            for (int j = 0; j < 27; ++j)
                s += x_sta[(b0 + row0 + r) * 27 + j] * w_sh[j * UNITS + u];
            igA[h][r] = sigmoidf_(s);
            asm("" : "+a"(igA[h][r]));
            cc[h * 2 + r] = 0.0f; hp[h * 2 + r] = 0.0f;
        }

    for (int t = 0; t < T_STEPS; ++t) {
        const int p = t & 1;
        __syncthreads();   // A[p] = [h_t | x_t] complete; A[p^1] free

        const unsigned short* Ap = &A_s[p][0][0];
        const int abase = mm * AP;

        #pragma unroll
        for (int h = 0; h < 2; ++h) {
            f32x4 ac0 = {0.f,0.f,0.f,0.f}, ac1 = {0.f,0.f,0.f,0.f}, ac2 = {0.f,0.f,0.f,0.f};
            #pragma unroll
            for (int ks = 0; ks < 8; ++ks) {
                const short8 a = *(const short8*)(Ap + abase + ks * 32 + qq * 8);
                MFMA3A(a, bw[ks][0][h], bw[ks][1][h], bw[ks][2][h]);
            }
            {   // x-contribution chunk (k=256..287), B from LDS, via BUILTINS
                // so the compiler inserts MFMA->VALU hazards for the shuffles.
                const short8 a = *(const short8*)(Ap + abase + UNITS + qq * 8);
                const int wb = (qq * G3 + wv * 32 + h * 16 + mm) * 8;
                const short8 bx0 = *(const short8*)(wih_s + wb);
                const short8 bx1 = *(const short8*)(wih_s + wb + UNITS * 8);
                const short8 bx2 = *(const short8*)(wih_s + wb + 2 * UNITS * 8);
                ac0 = __builtin_amdgcn_mfma_f32_16x16x32_bf16(a, bx0, ac0, 0, 0, 0);
                ac1 = __builtin_amdgcn_mfma_f32_16x16x32_bf16(a, bx1, ac1, 0, 0, 0);
                ac2 = __builtin_amdgcn_mfma_f32_16x16x32_bf16(a, bx2, ac2, 0, 0, 0);
            }

            // balance rows across quads: quads 2,3 take partner's r=2,3
            const bool lo = (qq < 2);
            float gf0, gf1, go0, go1, gg0, gg1;
            { const float v2 = __shfl(ac0[2], lane ^ 32, 64);
              const float v3 = __shfl(ac0[3], lane ^ 32, 64);
              gf0 = lo ? ac0[0] : v2;  gf1 = lo ? ac0[1] : v3; }
            { const float v2 = __shfl(ac1[2], lane ^ 32, 64);
              const float v3 = __shfl(ac1[3], lane ^ 32, 64);
              go0 = lo ? ac1[0] : v2;  go1 = lo ? ac1[1] : v3; }
            { const float v2 = __shfl(ac2[2], lane ^ 32, 64);
              const float v3 = __shfl(ac2[3], lane ^ 32, 64);
              gg0 = lo ? ac2[0] : v2;  gg1 = lo ? ac2[1] : v3; }

            const int u = h ? u1 : u0;
            #pragma unroll
            for (int r = 0; r < 2; ++r) {
                const int ci = h * 2 + r;
                const float h0  = hp[ci];                 // exact fp32 identity term
                const float gfv = (r ? gf1 : gf0) + bA[0][h] + h0;
                const float gov = (r ? go1 : go0) + bA[1][h] + h0;
                const float ggv = (r ? gg1 : gg0) + bA[2][h] + h0;
                const float f   = sigmoidf_(gfv);
                const float o   = sigmoidf_(gov);
                const float gt  = tanhf_(ggv);
                const float cn  = f * cc[ci] + igA[h][r] * gt;
                cc[ci] = cn;
                const float hn  = o * tanhf_(cn);
                hp[ci] = hn;
                A_s[p ^ 1][row0 + r][u] = f2bf(hn);
            }
        }

        // stage x_{t+1} into A[p^1]; prefetch x_{t+2}
        if (tid < MROWS * 32) {
            const int row = tid >> 5, j = tid & 31;
            A_s[p ^ 1][row][UNITS + j] = f2bf(xr);
            if (t + 2 < T_STEPS)
                xr = x_dyn[((size_t)(b0 + row) * T_STEPS + (t + 2)) * 32 + j];
        }
    }

    #pragma unroll
    for (int h = 0; h < 2; ++h)
        #pragma unroll
        for (int r = 0; r < 2; ++r)
            out[(size_t)(b0 + row0 + r) * UNITS + (h ? u1 : u0)] = hp[h * 2 + r];
}

extern "C" void kernel_launch(void* const* d_in, const int* in_sizes, int n_in,
                              void* d_out, int out_size, void* d_ws, size_t ws_size,
                              hipStream_t stream) {
    const float* x_dyn  = (const float*)d_in[0];
    const float* x_sta  = (const float*)d_in[1];
    const float* w_ih   = (const float*)d_in[2];
    const float* w_hh   = (const float*)d_in[3];
    const float* w_sh   = (const float*)d_in[4];
    const float* bias   = (const float*)d_in[5];
    const float* bias_s = (const float*)d_in[6];
    float* out = (float*)d_out;
    unsigned short* wp = (unsigned short*)d_ws;   // 288*768*2 = 442 KB scratch

    pack_weights<<<(KTOT * G3 + 255) / 256, 256, 0, stream>>>(w_ih, w_hh, wp);
    lstm_mfma<<<NWGS, 512, 0, stream>>>(x_dyn, x_sta, wp, w_sh, bias, bias_s, out);
}